// Round 3
// baseline (398.714 us; speedup 1.0000x reference)
//
#include <hip/hip_runtime.h>
#include <stdint.h>

// Problem constants
//   B=32, SQ=SK=512, DIM=512, H=8, HD=64, SCALE=0.125

typedef unsigned short u16;
typedef __attribute__((ext_vector_type(4))) float f32x4;
typedef __attribute__((ext_vector_type(8))) __bf16 bf16x8;
typedef __attribute__((ext_vector_type(4))) unsigned short u16x4;
typedef __attribute__((ext_vector_type(8))) unsigned short u16x8;

#define MFMA16(a, b, c) __builtin_amdgcn_mfma_f32_16x16x32_bf16((a), (b), (c), 0, 0, 0)

__device__ __forceinline__ u16 f2bf(float f) {
  unsigned u = __float_as_uint(f);
  u += 0x7fffu + ((u >> 16) & 1u);   // RNE
  return (u16)(u >> 16);
}
__device__ __forceinline__ float bf2f(u16 h) {
  return __uint_as_float(((unsigned)h) << 16);
}

// ---------------------------------------------------------------------------
// K0: weight prep. Wt[mat][n][k] = bf16(W[k][n]) for q,k,v; Wo -> hi/lo split,
// transposed to [n][k]. Reads are strided (L2-absorbed, 1MB), writes coalesced.
// ---------------------------------------------------------------------------
__global__ __launch_bounds__(256) void k_prep(
    const float* __restrict__ Wq, const float* __restrict__ Wk,
    const float* __restrict__ Wv, const float* __restrict__ Wo,
    u16* __restrict__ Wt, u16* __restrict__ WoHi, u16* __restrict__ WoLo) {
  int idx = blockIdx.x * 256 + threadIdx.x;   // 0..262143, k-major within n
  int n = idx >> 9, k = idx & 511;
  int src = k * 512 + n;                      // W[k][n]
  Wt[idx]          = f2bf(Wq[src]);
  Wt[262144 + idx] = f2bf(Wk[src]);
  Wt[524288 + idx] = f2bf(Wv[src]);
  float wo = Wo[src];
  u16 hi = f2bf(wo);
  WoHi[idx] = hi;
  WoLo[idx] = f2bf(wo - bf2f(hi));
}

// ---------------------------------------------------------------------------
// K1: projections. C[16384x512] = X[16384x512] @ W[512x512], per mat in z.
// Block 512 thr (8 waves, 2x4), tile 128x256, BK=32.
// Q,K stored bf16 [b,h,sq,hd]; V stored transposed bf16 [b,h,hd,sk].
// ---------------------------------------------------------------------------
__global__ __launch_bounds__(512) void k_proj(
    const float* __restrict__ Xq, const float* __restrict__ Xk, const float* __restrict__ Xv,
    const u16* __restrict__ Wt,
    u16* __restrict__ Qb, u16* __restrict__ Kb, u16* __restrict__ Vtb) {
  __shared__ u16 lA[128][40];
  __shared__ u16 lB[256][40];
  const int mat = blockIdx.z;
  const float* __restrict__ A = (mat == 0) ? Xq : (mat == 1) ? Xk : Xv;
  const u16* __restrict__ Bw = Wt + (size_t)mat * 262144;
  const int tid = threadIdx.x;
  const int lane = tid & 63, wid = tid >> 6;
  const int wm = wid >> 2, wn = wid & 3;       // wave grid 2 x 4
  const int m0 = blockIdx.y * 128, n0 = blockIdx.x * 256;
  const int fr = lane & 15, g = lane >> 4;
  const int arow = tid >> 3, acg = tid & 7;
  f32x4 acc[4][4] = {};

  for (int kt = 0; kt < 16; ++kt) {
    const int k0 = kt * 32;
#pragma unroll
    for (int p = 0; p < 2; ++p) {              // A: fp32 -> bf16 reg-stage
      int row = p * 64 + arow;
      f32x4 v = *(const f32x4*)&A[(size_t)(m0 + row) * 512 + k0 + acg * 4];
      u16x4 hv;
      hv[0] = f2bf(v[0]); hv[1] = f2bf(v[1]); hv[2] = f2bf(v[2]); hv[3] = f2bf(v[3]);
      *(u16x4*)&lA[row][acg * 4] = hv;
    }
#pragma unroll
    for (int p = 0; p < 2; ++p) {              // B: bf16 copy (row-major [n][k])
      int idx = p * 512 + tid;
      int row = idx >> 2, cg = idx & 3;
      *(u16x8*)&lB[row][cg * 8] = *(const u16x8*)&Bw[(size_t)(n0 + row) * 512 + k0 + cg * 8];
    }
    __syncthreads();
    bf16x8 af[4], bfr[4];
#pragma unroll
    for (int fm = 0; fm < 4; ++fm)
      af[fm] = *(const bf16x8*)&lA[wm * 64 + fm * 16 + fr][g * 8];
#pragma unroll
    for (int fn = 0; fn < 4; ++fn)
      bfr[fn] = *(const bf16x8*)&lB[wn * 64 + fn * 16 + fr][g * 8];
#pragma unroll
    for (int fm = 0; fm < 4; ++fm)
#pragma unroll
      for (int fn = 0; fn < 4; ++fn)
        acc[fm][fn] = MFMA16(af[fm], bfr[fn], acc[fm][fn]);
    __syncthreads();
  }

  if (mat < 2) {
    u16* __restrict__ Out = (mat == 0) ? Qb : Kb;
#pragma unroll
    for (int fm = 0; fm < 4; ++fm) {
#pragma unroll
      for (int fn = 0; fn < 4; ++fn) {
        int gn = n0 + wn * 64 + fn * 16 + fr;
        int hh = gn >> 6, hd = gn & 63;
#pragma unroll
        for (int r = 0; r < 4; ++r) {
          int gm = m0 + wm * 64 + fm * 16 + g * 4 + r;
          int b = gm >> 9, sq = gm & 511;
          Out[(size_t)((b * 8 + hh) * 512 + sq) * 64 + hd] = f2bf(acc[fm][fn][r]);
        }
      }
    }
  } else {
#pragma unroll
    for (int fm = 0; fm < 4; ++fm) {
      int gm0 = m0 + wm * 64 + fm * 16 + g * 4;
      int b = gm0 >> 9, sq0 = gm0 & 511;
#pragma unroll
      for (int fn = 0; fn < 4; ++fn) {
        int gn = n0 + wn * 64 + fn * 16 + fr;
        int hh = gn >> 6, hd = gn & 63;
        u16x4 pv;
        pv[0] = f2bf(acc[fm][fn][0]); pv[1] = f2bf(acc[fm][fn][1]);
        pv[2] = f2bf(acc[fm][fn][2]); pv[3] = f2bf(acc[fm][fn][3]);
        *(u16x4*)&Vtb[(size_t)((b * 8 + hh) * 64 + hd) * 512 + sq0] = pv;
      }
    }
  }
}

// ---------------------------------------------------------------------------
// K2: attention. One block per (b,h), 8 waves x 64 q-rows, flash-style online
// softmax, KVBLK=64. S kept in C-layout regs; P bounced through a per-wave
// 16x72 LDS buffer (C-layout -> A-layout). bias fp32, mask==0 -> -1e30.
// ---------------------------------------------------------------------------
__global__ __launch_bounds__(512, 2) void k_attn(
    const u16* __restrict__ Qb, const u16* __restrict__ Kb, const u16* __restrict__ Vtb,
    const int* __restrict__ mask, const float* __restrict__ bias,
    float* __restrict__ Obuf) {
  __shared__ u16 lP[8][16][72];
  const int tid = threadIdx.x, lane = tid & 63, w = tid >> 6;
  const int bid = blockIdx.x;
  // XCD swizzle: 8 heads of one batch land on one XCD (shared mask/bias in L2)
  const int xcd = bid & 7, jj = bid >> 3;
  const int b = xcd * 4 + (jj >> 3), h = jj & 7;
  const int bh = b * 8 + h;
  const int fr = lane & 15, g = lane >> 4;
  const int sq0 = w * 64;
  const u16* __restrict__ Qh = Qb + (size_t)bh * 32768;
  const u16* __restrict__ Kh = Kb + (size_t)bh * 32768;
  const u16* __restrict__ Vh = Vtb + (size_t)bh * 32768;

  bf16x8 qf[4][2];
#pragma unroll
  for (int fm = 0; fm < 4; ++fm)
#pragma unroll
    for (int kc = 0; kc < 2; ++kc)
      qf[fm][kc] = *(const bf16x8*)&Qh[(size_t)(sq0 + fm * 16 + fr) * 64 + kc * 32 + g * 8];

  f32x4 oacc[4][4] = {};
  float mrow[4][4], lrow[4][4];
#pragma unroll
  for (int fm = 0; fm < 4; ++fm)
#pragma unroll
    for (int r = 0; r < 4; ++r) { mrow[fm][r] = -1e30f; lrow[fm][r] = 0.f; }

  for (int kt = 0; kt < 8; ++kt) {
    const int sk0 = kt * 64;
    f32x4 sacc[4][4] = {};
#pragma unroll
    for (int kc = 0; kc < 2; ++kc) {
#pragma unroll
      for (int fn = 0; fn < 4; ++fn) {
        bf16x8 kf = *(const bf16x8*)&Kh[(size_t)(sk0 + fn * 16 + fr) * 64 + kc * 32 + g * 8];
#pragma unroll
        for (int fm = 0; fm < 4; ++fm)
          sacc[fm][fn] = MFMA16(qf[fm][kc], kf, sacc[fm][fn]);
      }
    }
    // scale + rel-pos bias + mask
#pragma unroll
    for (int fm = 0; fm < 4; ++fm) {
#pragma unroll
      for (int r = 0; r < 4; ++r) {
        const int sq = sq0 + fm * 16 + g * 4 + r;
#pragma unroll
        for (int fn = 0; fn < 4; ++fn) {
          const int sk = sk0 + fn * 16 + fr;
          float v = sacc[fm][fn][r] * 0.125f + bias[sq * 512 + sk];
          int mv = mask[((size_t)b * 512 + sq) * 512 + sk];
          sacc[fm][fn][r] = (mv != 0) ? v : -1e30f;
        }
      }
    }
    // per-16-row-frag online softmax + PV
#pragma unroll
    for (int fm = 0; fm < 4; ++fm) {
      float mn[4], sf[4];
#pragma unroll
      for (int r = 0; r < 4; ++r) {
        float v = fmaxf(fmaxf(sacc[fm][0][r], sacc[fm][1][r]),
                        fmaxf(sacc[fm][2][r], sacc[fm][3][r]));
        v = fmaxf(v, __shfl_xor(v, 1));
        v = fmaxf(v, __shfl_xor(v, 2));
        v = fmaxf(v, __shfl_xor(v, 4));
        v = fmaxf(v, __shfl_xor(v, 8));
        mn[r] = fmaxf(mrow[fm][r], v);
        sf[r] = __expf(mrow[fm][r] - mn[r]);
        mrow[fm][r] = mn[r];
      }
      float ps[4] = {0.f, 0.f, 0.f, 0.f};
#pragma unroll
      for (int fn = 0; fn < 4; ++fn) {
#pragma unroll
        for (int r = 0; r < 4; ++r) {
          float pe = __expf(sacc[fm][fn][r] - mn[r]);
          ps[r] += pe;
          lP[w][g * 4 + r][fn * 16 + fr] = f2bf(pe);
        }
      }
#pragma unroll
      for (int r = 0; r < 4; ++r) {
        float s = ps[r];
        s += __shfl_xor(s, 1);
        s += __shfl_xor(s, 2);
        s += __shfl_xor(s, 4);
        s += __shfl_xor(s, 8);
        lrow[fm][r] = lrow[fm][r] * sf[r] + s;
      }
#pragma unroll
      for (int fn = 0; fn < 4; ++fn)
#pragma unroll
        for (int r = 0; r < 4; ++r)
          oacc[fm][fn][r] *= sf[r];
      __builtin_amdgcn_wave_barrier();   // P writes before P reads (wave-private LDS)
#pragma unroll
      for (int kc = 0; kc < 2; ++kc) {
        bf16x8 pf = *(const bf16x8*)&lP[w][fr][kc * 32 + g * 8];
#pragma unroll
        for (int fn = 0; fn < 4; ++fn) {
          bf16x8 vf = *(const bf16x8*)&Vh[(size_t)(fn * 16 + fr) * 512 + sk0 + kc * 32 + g * 8];
          oacc[fm][fn] = MFMA16(pf, vf, oacc[fm][fn]);
        }
      }
      __builtin_amdgcn_wave_barrier();   // keep next fm's writes after these reads
    }
  }
  // epilogue: O / l -> Obuf[b, sq, h*64+hd] fp32
#pragma unroll
  for (int fm = 0; fm < 4; ++fm) {
#pragma unroll
    for (int fn = 0; fn < 4; ++fn) {
      const int hd = fn * 16 + fr;
#pragma unroll
      for (int r = 0; r < 4; ++r) {
        const int sq = sq0 + fm * 16 + g * 4 + r;
        Obuf[((size_t)b * 512 + sq) * 512 + h * 64 + hd] = oacc[fm][fn][r] / lrow[fm][r];
      }
    }
  }
}

// ---------------------------------------------------------------------------
// K3: output projection with 2-term bf16 split (hi/lo) for fp32-level accuracy:
// C = Oh@Wh + Oh@Wl + Ol@Wh + bo. Tile 128x256, 8 waves.
// ---------------------------------------------------------------------------
__global__ __launch_bounds__(512) void k_out(
    const float* __restrict__ Oin, const u16* __restrict__ WoHi, const u16* __restrict__ WoLo,
    const float* __restrict__ bo, float* __restrict__ out) {
  __shared__ u16 lAh[128][40], lAl[128][40];
  __shared__ u16 lBh[256][40], lBl[256][40];
  const int tid = threadIdx.x;
  const int lane = tid & 63, wid = tid >> 6;
  const int wm = wid >> 2, wn = wid & 3;
  const int m0 = blockIdx.y * 128, n0 = blockIdx.x * 256;
  const int fr = lane & 15, g = lane >> 4;
  const int arow = tid >> 3, acg = tid & 7;
  f32x4 acc[4][4] = {};

  for (int kt = 0; kt < 16; ++kt) {
    const int k0 = kt * 32;
#pragma unroll
    for (int p = 0; p < 2; ++p) {
      int row = p * 64 + arow;
      f32x4 v = *(const f32x4*)&Oin[(size_t)(m0 + row) * 512 + k0 + acg * 4];
      u16x4 hv, lv;
#pragma unroll
      for (int e = 0; e < 4; ++e) {
        u16 hb = f2bf(v[e]);
        hv[e] = hb;
        lv[e] = f2bf(v[e] - bf2f(hb));
      }
      *(u16x4*)&lAh[row][acg * 4] = hv;
      *(u16x4*)&lAl[row][acg * 4] = lv;
    }
#pragma unroll
    for (int p = 0; p < 2; ++p) {
      int idx = p * 512 + tid;
      int row = idx >> 2, cg = idx & 3;
      *(u16x8*)&lBh[row][cg * 8] = *(const u16x8*)&WoHi[(size_t)(n0 + row) * 512 + k0 + cg * 8];
      *(u16x8*)&lBl[row][cg * 8] = *(const u16x8*)&WoLo[(size_t)(n0 + row) * 512 + k0 + cg * 8];
    }
    __syncthreads();
    bf16x8 ah[4], al[4];
#pragma unroll
    for (int fm = 0; fm < 4; ++fm) {
      ah[fm] = *(const bf16x8*)&lAh[wm * 64 + fm * 16 + fr][g * 8];
      al[fm] = *(const bf16x8*)&lAl[wm * 64 + fm * 16 + fr][g * 8];
    }
#pragma unroll
    for (int fn = 0; fn < 4; ++fn) {
      bf16x8 bh = *(const bf16x8*)&lBh[wn * 64 + fn * 16 + fr][g * 8];
      bf16x8 bl = *(const bf16x8*)&lBl[wn * 64 + fn * 16 + fr][g * 8];
#pragma unroll
      for (int fm = 0; fm < 4; ++fm) {
        acc[fm][fn] = MFMA16(ah[fm], bh, acc[fm][fn]);
        acc[fm][fn] = MFMA16(ah[fm], bl, acc[fm][fn]);
        acc[fm][fn] = MFMA16(al[fm], bh, acc[fm][fn]);
      }
    }
    __syncthreads();
  }
#pragma unroll
  for (int fm = 0; fm < 4; ++fm) {
#pragma unroll
    for (int fn = 0; fn < 4; ++fn) {
      int gn = n0 + wn * 64 + fn * 16 + fr;
      float bv = bo[gn];
#pragma unroll
      for (int r = 0; r < 4; ++r) {
        int gm = m0 + wm * 64 + fm * 16 + g * 4 + r;
        out[(size_t)gm * 512 + gn] = acc[fm][fn][r] + bv;
      }
    }
  }
}

// ---------------------------------------------------------------------------
extern "C" void kernel_launch(void* const* d_in, const int* in_sizes, int n_in,
                              void* d_out, int out_size, void* d_ws, size_t ws_size,
                              hipStream_t stream) {
  (void)in_sizes; (void)n_in; (void)out_size; (void)ws_size;
  const float* query = (const float*)d_in[0];
  const float* key_t = (const float*)d_in[1];
  const float* value = (const float*)d_in[2];
  const int*   mask  = (const int*)d_in[3];
  const float* Wq    = (const float*)d_in[4];
  const float* Wk    = (const float*)d_in[5];
  const float* Wv    = (const float*)d_in[6];
  const float* Wo    = (const float*)d_in[7];
  const float* bo    = (const float*)d_in[8];
  const float* bias  = (const float*)d_in[9];
  float* out = (float*)d_out;

  char* p = (char*)d_ws;
  u16* Wt   = (u16*)p; p += (size_t)3 * 512 * 512 * 2;   // 1.5 MB
  u16* WoHi = (u16*)p; p += (size_t)512 * 512 * 2;       // 0.5 MB
  u16* WoLo = (u16*)p; p += (size_t)512 * 512 * 2;       // 0.5 MB
  u16* Qb   = (u16*)p; p += (size_t)32 * 8 * 512 * 64 * 2;   // 16.8 MB
  u16* Kb   = (u16*)p; p += (size_t)32 * 8 * 512 * 64 * 2;   // 16.8 MB
  u16* Vtb  = (u16*)p; p += (size_t)32 * 8 * 512 * 64 * 2;   // 16.8 MB
  float* Obuf = (float*)p;                                    // 33.5 MB

  k_prep<<<1024, 256, 0, stream>>>(Wq, Wk, Wv, Wo, Wt, WoHi, WoLo);
  k_proj<<<dim3(2, 128, 3), 512, 0, stream>>>(query, key_t, value, Wt, Qb, Kb, Vtb);
  k_attn<<<256, 512, 0, stream>>>(Qb, Kb, Vtb, mask, bias, Obuf);
  k_out<<<dim3(2, 128), 512, 0, stream>>>(Obuf, WoHi, WoLo, bo, out);
}

// Round 4
// 225.950 us; speedup vs baseline: 1.7646x; 1.7646x over previous
//
#include <hip/hip_runtime.h>
#include <stdint.h>

// Problem constants
//   B=32, SQ=SK=512, DIM=512, H=8, HD=64, SCALE=0.125

typedef unsigned short u16;
typedef __attribute__((ext_vector_type(4))) float f32x4;
typedef __attribute__((ext_vector_type(8))) __bf16 bf16x8;
typedef __attribute__((ext_vector_type(4))) unsigned short u16x4;
typedef __attribute__((ext_vector_type(8))) unsigned short u16x8;
typedef __attribute__((ext_vector_type(4))) int i32x4;
typedef __attribute__((ext_vector_type(4))) _Float16 f16x4;
typedef __attribute__((ext_vector_type(8))) _Float16 f16x8;

#define MFMA16(a, b, c) __builtin_amdgcn_mfma_f32_16x16x32_bf16((a), (b), (c), 0, 0, 0)

__device__ __forceinline__ u16 f2bf(float f) {
  unsigned u = __float_as_uint(f);
  u += 0x7fffu + ((u >> 16) & 1u);   // RNE
  return (u16)(u >> 16);
}
__device__ __forceinline__ float bf2f(u16 h) {
  return __uint_as_float(((unsigned)h) << 16);
}

// ---------------------------------------------------------------------------
// K0: weight prep. Wt[mat][n][k] = bf16(W[k][n]) for q,k,v; Wo -> hi/lo split,
// transposed to [n][k].
// ---------------------------------------------------------------------------
__global__ __launch_bounds__(256) void k_prep(
    const float* __restrict__ Wq, const float* __restrict__ Wk,
    const float* __restrict__ Wv, const float* __restrict__ Wo,
    u16* __restrict__ Wt, u16* __restrict__ WoHi, u16* __restrict__ WoLo) {
  int idx = blockIdx.x * 256 + threadIdx.x;   // 0..262143, k-major within n
  int n = idx >> 9, k = idx & 511;
  int src = k * 512 + n;                      // W[k][n]
  Wt[idx]          = f2bf(Wq[src]);
  Wt[262144 + idx] = f2bf(Wk[src]);
  Wt[524288 + idx] = f2bf(Wv[src]);
  float wo = Wo[src];
  u16 hi = f2bf(wo);
  WoHi[idx] = hi;
  WoLo[idx] = f2bf(wo - bf2f(hi));
}

// ---------------------------------------------------------------------------
// K0b: fused mask+bias -> fp16. MB[b][sq][sk] = mask ? fp16(bias) : -60000.
// Memory-bound: reads 32MB int + 1MB f32 (L3-cached), writes 16.8MB fp16.
// ---------------------------------------------------------------------------
__global__ __launch_bounds__(256) void k_mb(
    const int* __restrict__ mask, const float* __restrict__ bias,
    _Float16* __restrict__ MB) {
  size_t i8 = ((size_t)blockIdx.x * 256 + threadIdx.x) * 8;
  i32x4 m0 = *(const i32x4*)&mask[i8];
  i32x4 m1 = *(const i32x4*)&mask[i8 + 4];
  size_t bi = i8 & 262143;                    // idx % (512*512), bias broadcast over b
  f32x4 b0 = *(const f32x4*)&bias[bi];
  f32x4 b1 = *(const f32x4*)&bias[bi + 4];
  const _Float16 MASKED = (_Float16)(-60000.0f);
  f16x8 o;
#pragma unroll
  for (int e = 0; e < 4; ++e) {
    o[e]     = (m0[e] != 0) ? (_Float16)b0[e] : MASKED;
    o[e + 4] = (m1[e] != 0) ? (_Float16)b1[e] : MASKED;
  }
  *(f16x8*)&MB[i8] = o;
}

// ---------------------------------------------------------------------------
// K1: projections. C[16384x512] = X[16384x512] @ W[512x512], per mat in z.
// Block 512 thr (8 waves, 2x4), tile 128x256, BK=32.
// Q,K stored bf16 [b,h,sq,hd]; V stored transposed bf16 [b,h,hd,sk].
// ---------------------------------------------------------------------------
__global__ __launch_bounds__(512) void k_proj(
    const float* __restrict__ Xq, const float* __restrict__ Xk, const float* __restrict__ Xv,
    const u16* __restrict__ Wt,
    u16* __restrict__ Qb, u16* __restrict__ Kb, u16* __restrict__ Vtb) {
  __shared__ u16 lA[128][40];
  __shared__ u16 lB[256][40];
  const int mat = blockIdx.z;
  const float* __restrict__ A = (mat == 0) ? Xq : (mat == 1) ? Xk : Xv;
  const u16* __restrict__ Bw = Wt + (size_t)mat * 262144;
  const int tid = threadIdx.x;
  const int lane = tid & 63, wid = tid >> 6;
  const int wm = wid >> 2, wn = wid & 3;       // wave grid 2 x 4
  const int m0 = blockIdx.y * 128, n0 = blockIdx.x * 256;
  const int fr = lane & 15, g = lane >> 4;
  const int arow = tid >> 3, acg = tid & 7;
  f32x4 acc[4][4] = {};

  for (int kt = 0; kt < 16; ++kt) {
    const int k0 = kt * 32;
#pragma unroll
    for (int p = 0; p < 2; ++p) {              // A: fp32 -> bf16 reg-stage
      int row = p * 64 + arow;
      f32x4 v = *(const f32x4*)&A[(size_t)(m0 + row) * 512 + k0 + acg * 4];
      u16x4 hv;
      hv[0] = f2bf(v[0]); hv[1] = f2bf(v[1]); hv[2] = f2bf(v[2]); hv[3] = f2bf(v[3]);
      *(u16x4*)&lA[row][acg * 4] = hv;
    }
#pragma unroll
    for (int p = 0; p < 2; ++p) {              // B: bf16 copy (row-major [n][k])
      int idx = p * 512 + tid;
      int row = idx >> 2, cg = idx & 3;
      *(u16x8*)&lB[row][cg * 8] = *(const u16x8*)&Bw[(size_t)(n0 + row) * 512 + k0 + cg * 8];
    }
    __syncthreads();
    bf16x8 af[4], bfr[4];
#pragma unroll
    for (int fm = 0; fm < 4; ++fm)
      af[fm] = *(const bf16x8*)&lA[wm * 64 + fm * 16 + fr][g * 8];
#pragma unroll
    for (int fn = 0; fn < 4; ++fn)
      bfr[fn] = *(const bf16x8*)&lB[wn * 64 + fn * 16 + fr][g * 8];
#pragma unroll
    for (int fm = 0; fm < 4; ++fm)
#pragma unroll
      for (int fn = 0; fn < 4; ++fn)
        acc[fm][fn] = MFMA16(af[fm], bfr[fn], acc[fm][fn]);
    __syncthreads();
  }

  if (mat < 2) {
    u16* __restrict__ Out = (mat == 0) ? Qb : Kb;
#pragma unroll
    for (int fm = 0; fm < 4; ++fm) {
#pragma unroll
      for (int fn = 0; fn < 4; ++fn) {
        int gn = n0 + wn * 64 + fn * 16 + fr;
        int hh = gn >> 6, hd = gn & 63;
#pragma unroll
        for (int r = 0; r < 4; ++r) {
          int gm = m0 + wm * 64 + fm * 16 + g * 4 + r;
          int b = gm >> 9, sq = gm & 511;
          Out[(size_t)((b * 8 + hh) * 512 + sq) * 64 + hd] = f2bf(acc[fm][fn][r]);
        }
      }
    }
  } else {
#pragma unroll
    for (int fm = 0; fm < 4; ++fm) {
      int gm0 = m0 + wm * 64 + fm * 16 + g * 4;
      int b = gm0 >> 9, sq0 = gm0 & 511;
#pragma unroll
      for (int fn = 0; fn < 4; ++fn) {
        int gn = n0 + wn * 64 + fn * 16 + fr;
        int hh = gn >> 6, hd = gn & 63;
        u16x4 pv;
        pv[0] = f2bf(acc[fm][fn][0]); pv[1] = f2bf(acc[fm][fn][1]);
        pv[2] = f2bf(acc[fm][fn][2]); pv[3] = f2bf(acc[fm][fn][3]);
        *(u16x4*)&Vtb[(size_t)((b * 8 + hh) * 64 + hd) * 512 + sq0] = pv;
      }
    }
  }
}

// ---------------------------------------------------------------------------
// K2: attention with SWAPPED QK^T (mfma(K,Q) -> lane holds scores for one
// q-row). 4 waves x 32 q-rows, grid = (b,h,sq/128) = 1024 blocks = 4/CU.
// Softmax: in-lane reduce over 16 regs + 2 shfl_xor. P bounce: packed
// ds_write_b64 x4 + ds_read_b128 x2 per frag (conflict-free, 72-pad).
// Scores = 0.125*QK + MB (MB = fp16 bias or -60000 masked).
// ---------------------------------------------------------------------------
__global__ __launch_bounds__(256, 4) void k_attn(
    const u16* __restrict__ Qb, const u16* __restrict__ Kb, const u16* __restrict__ Vtb,
    const _Float16* __restrict__ MB, float* __restrict__ Obuf) {
  __shared__ __align__(16) u16 lP[4][2][16][72];
  const int tid = threadIdx.x, lane = tid & 63, w = tid >> 6;
  const int orig = blockIdx.x;
  // XCD swizzle: 4 consecutive-mod-8 blocks share b -> MB/Q/K/V L2 locality
  const int xcd = orig & 7, idx = orig >> 3;            // idx 0..127
  const int b = (idx & 3) * 8 + xcd;                    // 4 b's per XCD
  const int h = (idx >> 2) & 7, qq = idx >> 5;          // head, q-quarter
  const int bh = b * 8 + h;
  const int fr = lane & 15, g = lane >> 4;
  const int sq0 = qq * 128 + w * 32;
  const u16* __restrict__ Qh = Qb + (size_t)bh * 32768;
  const u16* __restrict__ Kh = Kb + (size_t)bh * 32768;
  const u16* __restrict__ Vh = Vtb + (size_t)bh * 32768;
  const _Float16* __restrict__ MBb = MB + (size_t)b * 262144;

  // Q fragments (B operand): row sq0+qfi*16+fr, k = kc*32+g*8
  bf16x8 qf[2][2];
#pragma unroll
  for (int qfi = 0; qfi < 2; ++qfi)
#pragma unroll
    for (int kc = 0; kc < 2; ++kc)
      qf[qfi][kc] = *(const bf16x8*)&Qh[(size_t)(sq0 + qfi * 16 + fr) * 64 + kc * 32 + g * 8];

  f32x4 oacc[2][4] = {};
  float mrow[2] = {-1e30f, -1e30f}, lrow[2] = {0.f, 0.f};

  for (int kt = 0; kt < 8; ++kt) {
    const int sk0 = kt * 64;
    // masked-bias loads (8B per lane, issued early, overlap MFMA)
    f16x4 mbv[2][4];
#pragma unroll
    for (int qfi = 0; qfi < 2; ++qfi)
#pragma unroll
      for (int fn = 0; fn < 4; ++fn)
        mbv[qfi][fn] = *(const f16x4*)&MBb[(size_t)(sq0 + qfi * 16 + fr) * 512 +
                                           sk0 + fn * 16 + g * 4];
    // QK^T, swapped: sacc lane holds q = qfi*16+fr (col), sk = fn*16+g*4+r (row)
    f32x4 sacc[2][4] = {};
#pragma unroll
    for (int fn = 0; fn < 4; ++fn) {
      bf16x8 kf0 = *(const bf16x8*)&Kh[(size_t)(sk0 + fn * 16 + fr) * 64 + g * 8];
      bf16x8 kf1 = *(const bf16x8*)&Kh[(size_t)(sk0 + fn * 16 + fr) * 64 + 32 + g * 8];
#pragma unroll
      for (int qfi = 0; qfi < 2; ++qfi) {
        sacc[qfi][fn] = MFMA16(kf0, qf[qfi][0], sacc[qfi][fn]);
        sacc[qfi][fn] = MFMA16(kf1, qf[qfi][1], sacc[qfi][fn]);
      }
    }
    // scale + masked bias
#pragma unroll
    for (int qfi = 0; qfi < 2; ++qfi)
#pragma unroll
      for (int fn = 0; fn < 4; ++fn)
#pragma unroll
        for (int r = 0; r < 4; ++r)
          sacc[qfi][fn][r] = sacc[qfi][fn][r] * 0.125f + (float)mbv[qfi][fn][r];

    // online softmax per q-frag: in-lane over 16 regs, then xor16/xor32
    float sf[2];
#pragma unroll
    for (int qfi = 0; qfi < 2; ++qfi) {
      float t0 = fmaxf(fmaxf(sacc[qfi][0][0], sacc[qfi][0][1]),
                       fmaxf(sacc[qfi][0][2], sacc[qfi][0][3]));
      float t1 = fmaxf(fmaxf(sacc[qfi][1][0], sacc[qfi][1][1]),
                       fmaxf(sacc[qfi][1][2], sacc[qfi][1][3]));
      float t2 = fmaxf(fmaxf(sacc[qfi][2][0], sacc[qfi][2][1]),
                       fmaxf(sacc[qfi][2][2], sacc[qfi][2][3]));
      float t3 = fmaxf(fmaxf(sacc[qfi][3][0], sacc[qfi][3][1]),
                       fmaxf(sacc[qfi][3][2], sacc[qfi][3][3]));
      float pm = fmaxf(fmaxf(t0, t1), fmaxf(t2, t3));
      pm = fmaxf(pm, __shfl_xor(pm, 16));
      pm = fmaxf(pm, __shfl_xor(pm, 32));
      float mn = fmaxf(mrow[qfi], pm);
      sf[qfi] = __expf(mrow[qfi] - mn);
      mrow[qfi] = mn;
      float ps = 0.f;
#pragma unroll
      for (int fn = 0; fn < 4; ++fn) {
        float p0 = __expf(sacc[qfi][fn][0] - mn);
        float p1 = __expf(sacc[qfi][fn][1] - mn);
        float p2 = __expf(sacc[qfi][fn][2] - mn);
        float p3 = __expf(sacc[qfi][fn][3] - mn);
        ps += (p0 + p1) + (p2 + p3);
        u16x4 pw;
        pw[0] = f2bf(p0); pw[1] = f2bf(p1); pw[2] = f2bf(p2); pw[3] = f2bf(p3);
        *(u16x4*)&lP[w][qfi][fr][fn * 16 + g * 4] = pw;   // packed b64 write
      }
      ps += __shfl_xor(ps, 16);
      ps += __shfl_xor(ps, 32);
      lrow[qfi] = lrow[qfi] * sf[qfi] + ps;
    }
    // rescale O by sf (redistribute: sf lives at lane q, oacc rows q=g*4+r)
#pragma unroll
    for (int qfi = 0; qfi < 2; ++qfi) {
#pragma unroll
      for (int r = 0; r < 4; ++r) {
        float sr = __shfl(sf[qfi], g * 4 + r);
#pragma unroll
        for (int fnh = 0; fnh < 4; ++fnh)
          oacc[qfi][fnh][r] *= sr;
      }
    }
    __builtin_amdgcn_wave_barrier();   // P writes before P reads (wave-private)
    // PV: A = P (from LDS), B = V fragments (reused across both q-frags)
#pragma unroll
    for (int kc = 0; kc < 2; ++kc) {
      bf16x8 pf0 = *(const bf16x8*)&lP[w][0][fr][kc * 32 + g * 8];
      bf16x8 pf1 = *(const bf16x8*)&lP[w][1][fr][kc * 32 + g * 8];
#pragma unroll
      for (int fnh = 0; fnh < 4; ++fnh) {
        bf16x8 vf = *(const bf16x8*)&Vh[(size_t)(fnh * 16 + fr) * 512 + sk0 + kc * 32 + g * 8];
        oacc[0][fnh] = MFMA16(pf0, vf, oacc[0][fnh]);
        oacc[1][fnh] = MFMA16(pf1, vf, oacc[1][fnh]);
      }
    }
    __builtin_amdgcn_wave_barrier();   // next kt's P writes after these reads
  }
  // epilogue: O / l -> Obuf[b, sq, h*64+hd] fp32
#pragma unroll
  for (int qfi = 0; qfi < 2; ++qfi) {
    float lr[4];
#pragma unroll
    for (int r = 0; r < 4; ++r)
      lr[r] = __shfl(lrow[qfi], g * 4 + r);
#pragma unroll
    for (int fnh = 0; fnh < 4; ++fnh) {
      const int hd = fnh * 16 + fr;
#pragma unroll
      for (int r = 0; r < 4; ++r) {
        const int sq = sq0 + qfi * 16 + g * 4 + r;
        Obuf[((size_t)b * 512 + sq) * 512 + h * 64 + hd] = oacc[qfi][fnh][r] / lr[r];
      }
    }
  }
}

// ---------------------------------------------------------------------------
// K3: output projection with 2-term bf16 split (hi/lo) for fp32-level accuracy:
// C = Oh@Wh + Oh@Wl + Ol@Wh + bo. Tile 128x256, 8 waves.
// ---------------------------------------------------------------------------
__global__ __launch_bounds__(512) void k_out(
    const float* __restrict__ Oin, const u16* __restrict__ WoHi, const u16* __restrict__ WoLo,
    const float* __restrict__ bo, float* __restrict__ out) {
  __shared__ u16 lAh[128][40], lAl[128][40];
  __shared__ u16 lBh[256][40], lBl[256][40];
  const int tid = threadIdx.x;
  const int lane = tid & 63, wid = tid >> 6;
  const int wm = wid >> 2, wn = wid & 3;
  const int m0 = blockIdx.y * 128, n0 = blockIdx.x * 256;
  const int fr = lane & 15, g = lane >> 4;
  const int arow = tid >> 3, acg = tid & 7;
  f32x4 acc[4][4] = {};

  for (int kt = 0; kt < 16; ++kt) {
    const int k0 = kt * 32;
#pragma unroll
    for (int p = 0; p < 2; ++p) {
      int row = p * 64 + arow;
      f32x4 v = *(const f32x4*)&Oin[(size_t)(m0 + row) * 512 + k0 + acg * 4];
      u16x4 hv, lv;
#pragma unroll
      for (int e = 0; e < 4; ++e) {
        u16 hb = f2bf(v[e]);
        hv[e] = hb;
        lv[e] = f2bf(v[e] - bf2f(hb));
      }
      *(u16x4*)&lAh[row][acg * 4] = hv;
      *(u16x4*)&lAl[row][acg * 4] = lv;
    }
#pragma unroll
    for (int p = 0; p < 2; ++p) {
      int idx = p * 512 + tid;
      int row = idx >> 2, cg = idx & 3;
      *(u16x8*)&lBh[row][cg * 8] = *(const u16x8*)&WoHi[(size_t)(n0 + row) * 512 + k0 + cg * 8];
      *(u16x8*)&lBl[row][cg * 8] = *(const u16x8*)&WoLo[(size_t)(n0 + row) * 512 + k0 + cg * 8];
    }
    __syncthreads();
    bf16x8 ah[4], al[4];
#pragma unroll
    for (int fm = 0; fm < 4; ++fm) {
      ah[fm] = *(const bf16x8*)&lAh[wm * 64 + fm * 16 + fr][g * 8];
      al[fm] = *(const bf16x8*)&lAl[wm * 64 + fm * 16 + fr][g * 8];
    }
#pragma unroll
    for (int fn = 0; fn < 4; ++fn) {
      bf16x8 bh = *(const bf16x8*)&lBh[wn * 64 + fn * 16 + fr][g * 8];
      bf16x8 bl = *(const bf16x8*)&lBl[wn * 64 + fn * 16 + fr][g * 8];
#pragma unroll
      for (int fm = 0; fm < 4; ++fm) {
        acc[fm][fn] = MFMA16(ah[fm], bh, acc[fm][fn]);
        acc[fm][fn] = MFMA16(ah[fm], bl, acc[fm][fn]);
        acc[fm][fn] = MFMA16(al[fm], bh, acc[fm][fn]);
      }
    }
    __syncthreads();
  }
#pragma unroll
  for (int fm = 0; fm < 4; ++fm) {
#pragma unroll
    for (int fn = 0; fn < 4; ++fn) {
      int gn = n0 + wn * 64 + fn * 16 + fr;
      float bv = bo[gn];
#pragma unroll
      for (int r = 0; r < 4; ++r) {
        int gm = m0 + wm * 64 + fm * 16 + g * 4 + r;
        out[(size_t)gm * 512 + gn] = acc[fm][fn][r] + bv;
      }
    }
  }
}

// ---------------------------------------------------------------------------
extern "C" void kernel_launch(void* const* d_in, const int* in_sizes, int n_in,
                              void* d_out, int out_size, void* d_ws, size_t ws_size,
                              hipStream_t stream) {
  (void)in_sizes; (void)n_in; (void)out_size; (void)ws_size;
  const float* query = (const float*)d_in[0];
  const float* key_t = (const float*)d_in[1];
  const float* value = (const float*)d_in[2];
  const int*   mask  = (const int*)d_in[3];
  const float* Wq    = (const float*)d_in[4];
  const float* Wk    = (const float*)d_in[5];
  const float* Wv    = (const float*)d_in[6];
  const float* Wo    = (const float*)d_in[7];
  const float* bo    = (const float*)d_in[8];
  const float* bias  = (const float*)d_in[9];
  float* out = (float*)d_out;

  char* p = (char*)d_ws;
  u16* Wt   = (u16*)p; p += (size_t)3 * 512 * 512 * 2;       // 1.5 MB
  u16* WoHi = (u16*)p; p += (size_t)512 * 512 * 2;           // 0.5 MB
  u16* WoLo = (u16*)p; p += (size_t)512 * 512 * 2;           // 0.5 MB
  u16* Qb   = (u16*)p; p += (size_t)32 * 8 * 512 * 64 * 2;   // 16.8 MB
  u16* Kb   = (u16*)p; p += (size_t)32 * 8 * 512 * 64 * 2;   // 16.8 MB
  u16* Vtb  = (u16*)p; p += (size_t)32 * 8 * 512 * 64 * 2;   // 16.8 MB
  float* Obuf = (float*)p; p += (size_t)32 * 512 * 512 * 4;  // 33.5 MB
  _Float16* MBp = (_Float16*)p;                              // 16.8 MB (total ~103.6 MB)

  k_prep<<<1024, 256, 0, stream>>>(Wq, Wk, Wv, Wo, Wt, WoHi, WoLo);
  k_mb<<<4096, 256, 0, stream>>>(mask, bias, MBp);
  k_proj<<<dim3(2, 128, 3), 512, 0, stream>>>(query, key_t, value, Wt, Qb, Kb, Vtb);
  k_attn<<<1024, 256, 0, stream>>>(Qb, Kb, Vtb, MBp, Obuf);
  k_out<<<dim3(2, 128), 512, 0, stream>>>(Obuf, WoHi, WoLo, bo, out);
}